// Round 2
// baseline (227.769 us; speedup 1.0000x reference)
//
#include <hip/hip_runtime.h>
#include <hip/hip_bf16.h>
#include <math.h>

constexpr int NTOK = 4096;
constexpr int CDIM = 256;
constexpr int MLPD = 1024;
constexpr int SPLIT = 4;
constexpr float EPS_LN = 1e-5f;

typedef __attribute__((ext_vector_type(8))) short bf16x8;
typedef __attribute__((ext_vector_type(4))) float floatx4;
typedef __attribute__((ext_vector_type(16))) float f32x16;
typedef unsigned short u16;
typedef unsigned int u32;

__device__ __forceinline__ u16 f2bf(float x) {
    union { float f; u32 u; } v; v.f = x;
    u32 r = v.u + 0x7fff + ((v.u >> 16) & 1);
    return (u16)(r >> 16);
}
__device__ __forceinline__ float bf2f(u16 u) {
    union { u32 i; float f; } v; v.i = ((u32)u) << 16; return v.f;
}
__device__ __forceinline__ u32 pkbf(float a, float b) {
    __hip_bfloat162 h = __float22bfloat162_rn(make_float2(a, b));
    union { __hip_bfloat162 h; u32 u; } v; v.h = h; return v.u;
}
__device__ __forceinline__ float gelu_exact(float x) {
    return 0.5f * x * (1.0f + erff(x * 0.70710678118654752f));
}

// ---------------- prep: [0,512) transpose rgb/dpt; [512,768) conv3x3; rest W->bf16
__global__ __launch_bounds__(256) void k_prep(const float* __restrict__ rgb,
                                              float* __restrict__ rgbT,
                                              const float* __restrict__ dpt,
                                              float* __restrict__ dptT,
                                              const float* __restrict__ xdpt,
                                              const float* __restrict__ w3,
                                              const float* __restrict__ b3,
                                              u16* __restrict__ y,
                                              const float* __restrict__ wq,
                                              const float* __restrict__ wk,
                                              const float* __restrict__ wv,
                                              const float* __restrict__ wo,
                                              const float* __restrict__ wde2,
                                              const float* __restrict__ wm1,
                                              const float* __restrict__ wm2,
                                              u16* __restrict__ arena) {
    int blk = blockIdx.x;
    int t = threadIdx.x;
    if (blk < 512) {
        const float* in = (blk < 256) ? rgb : dpt;
        float* out = (blk < 256) ? rgbT : dptT;
        int tb = blk & 255;
        int c0 = (tb & 63) * 64, r0 = (tb >> 6) * 64;
        __shared__ float T[64][65];
        int rr = t >> 4, cc = (t & 15) * 4;
#pragma unroll
        for (int i = 0; i < 4; ++i) {
            int row = i * 16 + rr;
            float4 v = *(const float4*)(in + (size_t)(r0 + row) * NTOK + c0 + cc);
            T[row][cc] = v.x; T[row][cc + 1] = v.y; T[row][cc + 2] = v.z; T[row][cc + 3] = v.w;
        }
        __syncthreads();
#pragma unroll
        for (int i = 0; i < 4; ++i) {
            int a = i * 16 + rr;
            float4 v;
            v.x = T[cc][a]; v.y = T[cc + 1][a]; v.z = T[cc + 2][a]; v.w = T[cc + 3][a];
            *(float4*)(out + (size_t)(c0 + a) * CDIM + r0 + cc) = v;
        }
    } else if (blk < 768) {
        __shared__ float nb[3][18];
        int n0 = (blk - 512) * 16;
        int yy = n0 >> 6, x0 = n0 & 63;
        if (t < 54) {
            int r = t / 18, cc = t % 18;
            int sy = yy - 1 + r, sx = x0 - 1 + cc;
            float v = 0.f;
            if (sy >= 0 && sy < 64 && sx >= 0 && sx < 64) {
                int r0 = 16 * sy + 7, c0 = 16 * sx + 7;
                v = 0.25f * (xdpt[r0 * 1024 + c0] + xdpt[r0 * 1024 + c0 + 1] +
                             xdpt[(r0 + 1) * 1024 + c0] + xdpt[(r0 + 1) * 1024 + c0 + 1]);
            }
            nb[r][cc] = v;
        }
        __syncthreads();
        float wv9[9];
#pragma unroll
        for (int i = 0; i < 9; ++i) wv9[i] = w3[t * 9 + i];
        float bb = b3[t];
#pragma unroll
        for (int k = 0; k < 16; ++k) {
            float acc = bb;
#pragma unroll
            for (int r = 0; r < 3; ++r)
#pragma unroll
                for (int kx = 0; kx < 3; ++kx) acc += wv9[r * 3 + kx] * nb[r][k + kx];
            y[(size_t)(n0 + k) * CDIM + t] = f2bf(fmaxf(acc, 0.f));
        }
    } else {
        int e0 = (blk - 768) * 1024 + t * 4;
        const float* src; int off;
        if (e0 < 65536)       { src = wq;   off = 0; }
        else if (e0 < 131072) { src = wk;   off = 65536; }
        else if (e0 < 196608) { src = wv;   off = 131072; }
        else if (e0 < 262144) { src = wo;   off = 196608; }
        else if (e0 < 327680) { src = wde2; off = 262144; }
        else if (e0 < 589824) { src = wm1;  off = 327680; }
        else                  { src = wm2;  off = 589824; }
        float4 v = *(const float4*)(src + (e0 - off));
        uint2 o; o.x = pkbf(v.x, v.y); o.y = pkbf(v.z, v.w);
        *(uint2*)(arena + e0) = o;
    }
}

// ---------------- token-major LayerNorm (dual-set via blockIdx.y) ----------------
__global__ __launch_bounds__(256) void k_lnT(const void* __restrict__ xA,
                                             const float* __restrict__ gA,
                                             const float* __restrict__ bA,
                                             void* __restrict__ yA,
                                             const void* __restrict__ xB,
                                             const float* __restrict__ gB,
                                             const float* __restrict__ bB,
                                             void* __restrict__ yB,
                                             const u16* __restrict__ pe,
                                             const float* __restrict__ pos,
                                             int xf32) {
    const void* x; const float* g; const float* bb; void* y;
    if (blockIdx.y == 0) { x = xA; g = gA; bb = bA; y = yA; }
    else                 { x = xB; g = gB; bb = bB; y = yB; }
    int n = blockIdx.x * 4 + (threadIdx.x >> 6);
    int lane = threadIdx.x & 63;
    int c = lane * 4;
    float4 xv;
    if (xf32) {
        xv = *((const float4*)x + (size_t)n * 64 + lane);
    } else {
        ushort4 u = *((const ushort4*)x + (size_t)n * 64 + lane);
        xv = make_float4(bf2f(u.x), bf2f(u.y), bf2f(u.z), bf2f(u.w));
    }
    float s = xv.x + xv.y + xv.z + xv.w;
    float s2 = xv.x * xv.x + xv.y * xv.y + xv.z * xv.z + xv.w * xv.w;
#pragma unroll
    for (int off = 1; off < 64; off <<= 1) {
        s += __shfl_xor(s, off, 64);
        s2 += __shfl_xor(s2, off, 64);
    }
    float mu = s * (1.0f / 256.0f);
    float var = s2 * (1.0f / 256.0f) - mu * mu;
    float rsd = rsqrtf(var + EPS_LN);
    float4 g4 = *(const float4*)(g + c);
    float4 b4 = *(const float4*)(bb + c);
    float4 o;
    o.x = (xv.x - mu) * rsd * g4.x + b4.x;
    o.y = (xv.y - mu) * rsd * g4.y + b4.y;
    o.z = (xv.z - mu) * rsd * g4.z + b4.z;
    o.w = (xv.w - mu) * rsd * g4.w + b4.w;
    if (pe) {
        float4 p4 = *(const float4*)(pos + c);
        ushort4 pu = *((const ushort4*)pe + (size_t)n * 64 + lane);
        o.x += p4.x + bf2f(pu.x);
        o.y += p4.y + bf2f(pu.y);
        o.z += p4.z + bf2f(pu.z);
        o.w += p4.w + bf2f(pu.w);
    }
    ushort4 ou;
    ou.x = f2bf(o.x); ou.y = f2bf(o.y); ou.z = f2bf(o.z); ou.w = f2bf(o.w);
    *((ushort4*)y + (size_t)n * 64 + lane) = ou;
}

// ---------------- bf16 MFMA GEMM, 512 threads, in-block split-K ------------------
// flags: 1 GELU | 2 swap-out [m][4096] | 4 res f32 [N][M] | 8 res bf16 [N][M]
//      | 16 smul=log2e/scl | 32 W bf16 | 64 head-major out [m>>5][tok][m&31]
#define LDB 72
__global__ __launch_bounds__(512) void k_bmm(const u16* __restrict__ X0, const void* __restrict__ W0,
                                             const float* __restrict__ B0, void* __restrict__ Y0, int f0,
                                             const u16* __restrict__ X1, const void* __restrict__ W1,
                                             const float* __restrict__ B1, void* __restrict__ Y1, int f1,
                                             const u16* __restrict__ X2, const void* __restrict__ W2,
                                             const float* __restrict__ B2, void* __restrict__ Y2, int f2,
                                             const void* __restrict__ res, const float* __restrict__ scl,
                                             int M, int K) {
    const u16* X; const void* Wp; const float* bias; void* Yp; int flags;
    if (blockIdx.z == 0)      { X = X0; Wp = W0; bias = B0; Yp = Y0; flags = f0; }
    else if (blockIdx.z == 1) { X = X1; Wp = W1; bias = B1; Yp = Y1; flags = f1; }
    else                      { X = X2; Wp = W2; bias = B2; Yp = Y2; flags = f2; }
    __shared__ u16 Xs[2][64 * LDB];
    __shared__ u16 Ws[2][64 * LDB];
    float* Cred = (float*)&Xs[0][0];

    int tid = threadIdx.x;
    int kg = tid >> 8;
    int t = tid & 255;
    int wid = t >> 6, lane = t & 63;
    int lo16 = lane & 15, quad = lane >> 4;
    int wy = wid & 1, wx = wid >> 1;
    int n0 = blockIdx.x * 64, m0 = blockIdx.y * 64;
    int srow = t >> 2, sseg = t & 3;
    int Khalf = K >> 1;
    int kbase = kg * Khalf;

    floatx4 acc[2][2];
#pragma unroll
    for (int i = 0; i < 2; ++i)
#pragma unroll
        for (int j = 0; j < 2; ++j) acc[i][j] = floatx4{0.f, 0.f, 0.f, 0.f};

    for (int k0 = 0; k0 < Khalf; k0 += 64) {
        int kk = kbase + k0;
        const u16* xp = X + (size_t)(n0 + srow) * K + kk + sseg * 16;
        uint4 xr0 = *(const uint4*)xp;
        uint4 xr1 = *(const uint4*)(xp + 8);
        uint4 wb0, wb1;
        if (flags & 32) {
            const u16* wp = (const u16*)Wp + (size_t)(m0 + srow) * K + kk + sseg * 16;
            wb0 = *(const uint4*)wp;
            wb1 = *(const uint4*)(wp + 8);
        } else {
            const float* wp = (const float*)Wp + (size_t)(m0 + srow) * K + kk + sseg * 16;
            float4 w0 = *(const float4*)wp;
            float4 w1 = *(const float4*)(wp + 4);
            float4 w2 = *(const float4*)(wp + 8);
            float4 w3 = *(const float4*)(wp + 12);
            wb0.x = pkbf(w0.x, w0.y); wb0.y = pkbf(w0.z, w0.w);
            wb0.z = pkbf(w1.x, w1.y); wb0.w = pkbf(w1.z, w1.w);
            wb1.x = pkbf(w2.x, w2.y); wb1.y = pkbf(w2.z, w2.w);
            wb1.z = pkbf(w3.x, w3.y); wb1.w = pkbf(w3.z, w3.w);
        }
        __syncthreads();
        *(uint4*)&Xs[kg][srow * LDB + sseg * 16] = xr0;
        *(uint4*)&Xs[kg][srow * LDB + sseg * 16 + 8] = xr1;
        *(uint4*)&Ws[kg][srow * LDB + sseg * 16] = wb0;
        *(uint4*)&Ws[kg][srow * LDB + sseg * 16 + 8] = wb1;
        __syncthreads();

        const u16* As = (flags & 2) ? &Ws[kg][0] : &Xs[kg][0];
        const u16* Bs = (flags & 2) ? &Xs[kg][0] : &Ws[kg][0];
#pragma unroll
        for (int h = 0; h < 2; ++h) {
            int ko = h * 32 + quad * 8;
            bf16x8 a0 = *(const bf16x8*)&As[(wy * 32 + lo16) * LDB + ko];
            bf16x8 a1 = *(const bf16x8*)&As[(wy * 32 + 16 + lo16) * LDB + ko];
            bf16x8 b0 = *(const bf16x8*)&Bs[(wx * 32 + lo16) * LDB + ko];
            bf16x8 b1 = *(const bf16x8*)&Bs[(wx * 32 + 16 + lo16) * LDB + ko];
            acc[0][0] = __builtin_amdgcn_mfma_f32_16x16x32_bf16(a0, b0, acc[0][0], 0, 0, 0);
            acc[0][1] = __builtin_amdgcn_mfma_f32_16x16x32_bf16(a0, b1, acc[0][1], 0, 0, 0);
            acc[1][0] = __builtin_amdgcn_mfma_f32_16x16x32_bf16(a1, b0, acc[1][0], 0, 0, 0);
            acc[1][1] = __builtin_amdgcn_mfma_f32_16x16x32_bf16(a1, b1, acc[1][1], 0, 0, 0);
        }
    }

    __syncthreads();
    if (kg == 1) {
        float* c = &Cred[t * 17];
#pragma unroll
        for (int i = 0; i < 2; ++i)
#pragma unroll
            for (int j = 0; j < 2; ++j)
#pragma unroll
                for (int r = 0; r < 4; ++r) c[(i * 2 + j) * 4 + r] = acc[i][j][r];
    }
    __syncthreads();
    if (kg == 1) return;
    {
        const float* c = &Cred[t * 17];
#pragma unroll
        for (int i = 0; i < 2; ++i)
#pragma unroll
            for (int j = 0; j < 2; ++j)
#pragma unroll
                for (int r = 0; r < 4; ++r) acc[i][j][r] += c[(i * 2 + j) * 4 + r];
    }

    u16* Y = (u16*)Yp;
    if (flags & 2) {
#pragma unroll
        for (int i = 0; i < 2; ++i)
#pragma unroll
            for (int r = 0; r < 4; ++r) {
                int ch = m0 + wy * 32 + i * 16 + quad * 4 + r;
                float bb = bias[ch];
#pragma unroll
                for (int j = 0; j < 2; ++j) {
                    int tok = n0 + wx * 32 + j * 16 + lo16;
                    Y[(size_t)ch * NTOK + tok] = f2bf(acc[i][j][r] + bb);
                }
            }
    } else {
        float smul = (flags & 16) ? 1.4426950408889634f / scl[0] : 1.0f;
        float bj0 = bias[m0 + wx * 32 + lo16];
        float bj1 = bias[m0 + wx * 32 + 16 + lo16];
        const float* rf = (const float*)res;
        const u16* rb = (const u16*)res;
#pragma unroll
        for (int i = 0; i < 2; ++i)
#pragma unroll
            for (int j = 0; j < 2; ++j) {
                int ch = m0 + wx * 32 + j * 16 + lo16;
                float bb = j ? bj1 : bj0;
#pragma unroll
                for (int r = 0; r < 4; ++r) {
                    int tok = n0 + wy * 32 + i * 16 + quad * 4 + r;
                    float v = (acc[i][j][r] + bb) * smul;
                    if (flags & 1) v = gelu_exact(v);
                    if (flags & 4) v += rf[(size_t)tok * M + ch];
                    if (flags & 8) v += bf2f(rb[(size_t)tok * M + ch]);
                    if (flags & 64)
                        Y[((size_t)(ch >> 5) * NTOK + tok) * 32 + (ch & 31)] = f2bf(v);
                    else
                        Y[(size_t)tok * M + ch] = f2bf(v);
                }
            }
    }
}

// ---------------- split-K flash attention, 32x32 MFMA, NO LDS -------------------
// grid (32, 8, SPLIT): block = 128 queries (4 waves x 32q) x 1024 keys (split sp).
// All MFMA operands are loaded global->VGPR directly in fragment layout (16 B
// contiguous per lane): K A-frag = K[key][8hi..], V B-frag = V[d=ql][key 8hi..].
// No barriers, no ds ops -> LDS pipe idle, waves run unsynchronized; intra-block
// redundant K/V loads (4 waves identical) are absorbed by L1. Softmax stays in
// registers; PV A-fragments rebuilt via one cross-half shuffle per packed word.
__global__ __launch_bounds__(256) void k_fattn(const u16* __restrict__ Qh,
                                               const u16* __restrict__ Kh,
                                               const u16* __restrict__ Vc,
                                               u16* __restrict__ Op,
                                               float* __restrict__ Lp) {
    int h = blockIdx.y;
    int q0 = blockIdx.x * 128;
    int sp = blockIdx.z;
    int tid = threadIdx.x;
    int wid = tid >> 6, lane = tid & 63;
    int ql = lane & 31, hi = lane >> 5;
    int qtok = q0 + wid * 32 + ql;

    // stationary Q as B-operand: col=q=ql, k=d (two 16-wide d-halves)
    const u16* qp = Qh + ((size_t)h * NTOK + qtok) * 32 + hi * 8;
    bf16x8 bq0 = *(const bf16x8*)(qp);
    bf16x8 bq1 = *(const bf16x8*)(qp + 16);

    int kbase = sp * (NTOK / SPLIT);
    const int NITER = NTOK / SPLIT / 64;

    // K A-frag base: row=key (starts at kbase+ql), d byte-offset hi*16 (ak1: +32B)
    const u16* kp = Kh + ((size_t)h * NTOK + kbase + ql) * 32 + hi * 8;
    // V B-frag base: row=d=ql, key offset hi*8 (bv1: +16 keys)
    const u16* vp = Vc + (size_t)(h * 32 + ql) * NTOK + kbase + hi * 8;

    f32x16 oacc = {0.f, 0.f, 0.f, 0.f, 0.f, 0.f, 0.f, 0.f,
                   0.f, 0.f, 0.f, 0.f, 0.f, 0.f, 0.f, 0.f};
    const f32x16 zv = {0.f, 0.f, 0.f, 0.f, 0.f, 0.f, 0.f, 0.f,
                       0.f, 0.f, 0.f, 0.f, 0.f, 0.f, 0.f, 0.f};
    float l = 0.f;

    for (int kt = 0; kt < NITER; ++kt) {
        // issue all 8 fragment loads for this 64-key tile up front (MLP=8)
        const u16* kq = kp + (size_t)kt * 64 * 32;
        const u16* vq = vp + kt * 64;
        bf16x8 ak0a = *(const bf16x8*)(kq);
        bf16x8 ak1a = *(const bf16x8*)(kq + 16);
        bf16x8 ak0b = *(const bf16x8*)(kq + 32 * 32);
        bf16x8 ak1b = *(const bf16x8*)(kq + 32 * 32 + 16);
        bf16x8 bv0a = *(const bf16x8*)(vq);
        bf16x8 bv1a = *(const bf16x8*)(vq + 16);
        bf16x8 bv0b = *(const bf16x8*)(vq + 32);
        bf16x8 bv1b = *(const bf16x8*)(vq + 48);

#pragma unroll
        for (int sub = 0; sub < 2; ++sub) {
            // S^T[key][q] over 32 keys, d=32 via two K=16 MFMAs (C of first = zv)
            f32x16 s = __builtin_amdgcn_mfma_f32_32x32x16_bf16(sub ? ak0b : ak0a, bq0, zv, 0, 0, 0);
            s = __builtin_amdgcn_mfma_f32_32x32x16_bf16(sub ? ak1b : ak1a, bq1, s, 0, 0, 0);
            // p = exp2(s) (scores O(1), no max); pack pairs of adjacent keys:
            // u[t] = P[q][keys (2t&3)+8*(t>>1)+4*hi .. +1]
            u32 u[8], px[8];
#pragma unroll
            for (int t = 0; t < 8; ++t) {
                float pa = __builtin_amdgcn_exp2f(s[2 * t]);
                float pb = __builtin_amdgcn_exp2f(s[2 * t + 1]);
                l += pa + pb;
                u[t] = pkbf(pa, pb);
            }
#pragma unroll
            for (int t = 0; t < 8; ++t) px[t] = (u32)__shfl_xor((int)u[t], 32, 64);
            // rebuild PV A-fragments (row=q, k=key): m=0 -> keys sub*32+0..15,
            // m=1 -> keys sub*32+16..31; slots verified against acc layout.
            uint4 wa, wb;
            wa.x = hi ? px[2] : u[0];
            wa.y = hi ? px[3] : u[1];
            wa.z = hi ? u[2] : px[0];
            wa.w = hi ? u[3] : px[1];
            wb.x = hi ? px[6] : u[4];
            wb.y = hi ? px[7] : u[5];
            wb.z = hi ? u[6] : px[4];
            wb.w = hi ? u[7] : px[5];
            union { uint4 q; bf16x8 v; } pa0, pa1;
            pa0.q = wa; pa1.q = wb;
            oacc = __builtin_amdgcn_mfma_f32_32x32x16_bf16(pa0.v, sub ? bv0b : bv0a, oacc, 0, 0, 0);
            oacc = __builtin_amdgcn_mfma_f32_32x32x16_bf16(pa1.v, sub ? bv1b : bv1a, oacc, 0, 0, 0);
        }
    }

    // l for q=ql: this lane summed its hi-half of keys; combine halves
    l += __shfl_xor(l, 32, 64);

    // O partial: rows q = (r&3)+8*(r>>2)+4*hi, col d = ql
    size_t obase = ((size_t)(sp * 8 + h) * NTOK + q0 + wid * 32) * 32 + ql;
#pragma unroll
    for (int r = 0; r < 16; ++r) {
        int qrow = (r & 3) + 8 * (r >> 2) + 4 * hi;
        Op[obase + (size_t)qrow * 32] = f2bf(oacc[r]);
    }
    if (hi == 0) Lp[(size_t)(sp * 8 + h) * NTOK + qtok] = l;
}

// ---------------- combine split partials -> fused bf16 [tok][256] ----------------
__global__ __launch_bounds__(256) void k_comb(const u16* __restrict__ Op,
                                              const float* __restrict__ Lp,
                                              u16* __restrict__ fused) {
    int n = blockIdx.x * 4 + (threadIdx.x >> 6);
    int lane = threadIdx.x & 63;
    int c = lane * 4;
    int h = c >> 5, d = c & 31;
    float4 o = {0.f, 0.f, 0.f, 0.f};
    float l = 0.f;
#pragma unroll
    for (int s = 0; s < SPLIT; ++s) {
        size_t base = ((size_t)(s * 8 + h) * NTOK + n) * 32 + d;
        uint2 u = *(const uint2*)(Op + base);
        o.x += bf2f((u16)(u.x & 0xffff)); o.y += bf2f((u16)(u.x >> 16));
        o.z += bf2f((u16)(u.y & 0xffff)); o.w += bf2f((u16)(u.y >> 16));
        l += Lp[(size_t)(s * 8 + h) * NTOK + n];
    }
    float inv = 1.0f / l;
    uint2 w;
    w.x = pkbf(o.x * inv, o.y * inv);
    w.y = pkbf(o.z * inv, o.w * inv);
    *(uint2*)(fused + (size_t)n * CDIM + c) = w;
}

// ---------------- fused LN2 + transpose: out2T bf16 [4096][256] -> out f32 [256][4096]
__global__ __launch_bounds__(256) void k_lntr(const u16* __restrict__ x,
                                              const float* __restrict__ g,
                                              const float* __restrict__ b,
                                              float* __restrict__ out) {
    __shared__ float T[16][260];
    int n0 = blockIdx.x * 16;
    int t = threadIdx.x;
    int tk = t >> 4, seg = t & 15;
    float v[16];
    {
        const u16* p = x + (size_t)(n0 + tk) * CDIM + seg * 16;
        uint4 a = *(const uint4*)p;
        uint4 bq = *(const uint4*)(p + 8);
        u32 uu[8] = {a.x, a.y, a.z, a.w, bq.x, bq.y, bq.z, bq.w};
#pragma unroll
        for (int i = 0; i < 8; ++i) {
            v[2 * i] = bf2f((u16)(uu[i] & 0xffff));
            v[2 * i + 1] = bf2f((u16)(uu[i] >> 16));
        }
    }
    float s = 0.f, s2 = 0.f;
#pragma unroll
    for (int i = 0; i < 16; ++i) { s += v[i]; s2 += v[i] * v[i]; }
#pragma unroll
    for (int off = 1; off < 16; off <<= 1) {
        s += __shfl_xor(s, off, 64);
        s2 += __shfl_xor(s2, off, 64);
    }
    float mu = s * (1.0f / 256.0f);
    float var = s2 * (1.0f / 256.0f) - mu * mu;
    float rsd = rsqrtf(var + EPS_LN);
#pragma unroll
    for (int i = 0; i < 16; ++i) {
        int c = seg * 16 + i;
        T[tk][c] = (v[i] - mu) * rsd * g[c] + b[c];
    }
    __syncthreads();
    int c = t;
    float o[16];
#pragma unroll
    for (int j = 0; j < 16; ++j) o[j] = T[j][c];
    float* dst = out + (size_t)c * NTOK + n0;
#pragma unroll
    for (int j = 0; j < 4; ++j) {
        float4 w = {o[4 * j], o[4 * j + 1], o[4 * j + 2], o[4 * j + 3]};
        *(float4*)(dst + 4 * j) = w;
    }
}

// ------------------------------------------------------------------------------
extern "C" void kernel_launch(void* const* d_in, const int* in_sizes, int n_in,
                              void* d_out, int out_size, void* d_ws, size_t ws_size,
                              hipStream_t stream) {
    const float* rgb    = (const float*)d_in[0];
    const float* dpt    = (const float*)d_in[1];
    const float* x_dpt  = (const float*)d_in[2];
    const float* wq     = (const float*)d_in[3];
    const float* bq     = (const float*)d_in[4];
    const float* wk     = (const float*)d_in[5];
    const float* bk     = (const float*)d_in[6];
    const float* wv     = (const float*)d_in[7];
    const float* bv     = (const float*)d_in[8];
    const float* wo     = (const float*)d_in[9];
    const float* bo     = (const float*)d_in[10];
    const float* g_rgb  = (const float*)d_in[11];
    const float* b_rgb  = (const float*)d_in[12];
    const float* g_dpt  = (const float*)d_in[13];
    const float* b_dpt  = (const float*)d_in[14];
    const float* g1     = (const float*)d_in[15];
    const float* b1     = (const float*)d_in[16];
    const float* g2     = (const float*)d_in[17];
    const float* b2     = (const float*)d_in[18];
    const float* w_mlp1 = (const float*)d_in[19];
    const float* b_mlp1 = (const float*)d_in[20];
    const float* w_mlp2 = (const float*)d_in[21];
    const float* b_mlp2 = (const float*)d_in[22];
    const float* w_de1  = (const float*)d_in[23];
    const float* b_de1  = (const float*)d_in[24];
    const float* w_de2  = (const float*)d_in[25];
    const float* b_de2  = (const float*)d_in[26];
    const float* pos    = (const float*)d_in[27];
    const float* scale  = (const float*)d_in[28];
    float* out = (float*)d_out;

    char* base = (char*)d_ws;
    const size_t MB = 1u << 20;
    float* rgbT    = (float*)(base + 0 * MB);
    float* dptT    = (float*)(base + 4 * MB);
    u16*   outT    = (u16*)(base + 4 * MB);
    float* Lp      = (float*)(base + 6 * MB);    // fattn..comb (512 KB)
    u16*   out_lnT = (u16*)(base + 6 * MB);      // ln1..mlp2 (after comb)
    u16*   relu3T  = (u16*)(base + 8 * MB);      // prep..peGEMM
    u16*   Op      = (u16*)(base + 8 * MB);      // fattn..comb (8 MB, after QKV consumed)
    u16*   hT      = (u16*)(base + 8 * MB);      // mlp1..mlp2 (after comb)
    u16*   peT     = (u16*)(base + 10 * MB);     // peGEMM..LN
    u16*   aqT     = (u16*)(base + 12 * MB);     // LN..QKV
    u16*   akvT    = (u16*)(base + 14 * MB);     // LN..QKV
    u16*   Qhm     = (u16*)(base + 16 * MB);     // QKV..fattn
    u16*   out2T   = (u16*)(base + 16 * MB);     // mlp2..ln2
    u16*   Khm     = (u16*)(base + 18 * MB);
    u16*   Vcm     = (u16*)(base + 20 * MB);
    u16*   fusedT  = (u16*)(base + 22 * MB);     // comb..wo
    u16*   arena   = (u16*)(base + 24 * MB);     // bf16 weights

    bool aw = ws_size >= 26 * MB;
    int wf = aw ? 32 : 0;
    const void* Wq  = aw ? (const void*)(arena + 0)      : (const void*)wq;
    const void* Wk  = aw ? (const void*)(arena + 65536)  : (const void*)wk;
    const void* Wv  = aw ? (const void*)(arena + 131072) : (const void*)wv;
    const void* Wo  = aw ? (const void*)(arena + 196608) : (const void*)wo;
    const void* Wd2 = aw ? (const void*)(arena + 262144) : (const void*)w_de2;
    const void* Wm1 = aw ? (const void*)(arena + 327680) : (const void*)w_mlp1;
    const void* Wm2 = aw ? (const void*)(arena + 589824) : (const void*)w_mlp2;

    // 1: transposes + downsample/conv3x3 + weight conversion
    k_prep<<<aw ? 512 + 256 + 832 : 512 + 256, 256, 0, stream>>>(
        rgb, rgbT, dpt, dptT, x_dpt, w_de1, b_de1, relu3T,
        wq, wk, wv, wo, w_de2, w_mlp1, w_mlp2, arena);
    // 2: pe = 1x1(relu3)
    k_bmm<<<dim3(64, 4, 1), 512, 0, stream>>>(relu3T, Wd2, b_de2, peT, wf,
                                              nullptr, nullptr, nullptr, nullptr, 0,
                                              nullptr, nullptr, nullptr, nullptr, 0,
                                              nullptr, nullptr, CDIM, CDIM);
    // 3: both LayerNorms (+pos+pe)
    k_lnT<<<dim3(1024, 2), 256, 0, stream>>>(rgbT, g_rgb, b_rgb, aqT,
                                             dptT, g_dpt, b_dpt, akvT,
                                             peT, pos, 1);
    // 4: QKV (q scaled+head-major, k head-major, v channel-major)
    k_bmm<<<dim3(64, 4, 3), 512, 0, stream>>>(aqT, Wq, bq, Qhm, wf | 16 | 64,
                                              akvT, Wk, bk, Khm, wf | 64,
                                              akvT, Wv, bv, Vcm, wf | 2,
                                              nullptr, scale, CDIM, CDIM);
    // 5: split-K flash attention (32x32 MFMA, register-resident P, no LDS)
    k_fattn<<<dim3(32, 8, SPLIT), 256, 0, stream>>>(Qhm, Khm, Vcm, Op, Lp);
    // 6: combine partials
    k_comb<<<1024, 256, 0, stream>>>(Op, Lp, fusedT);
    // 7: output projection + residual(rgbT)
    k_bmm<<<dim3(64, 4, 1), 512, 0, stream>>>(fusedT, Wo, bo, outT, wf | 4,
                                              nullptr, nullptr, nullptr, nullptr, 0,
                                              nullptr, nullptr, nullptr, nullptr, 0,
                                              rgbT, nullptr, CDIM, CDIM);
    // 8: LN1
    k_lnT<<<dim3(1024, 1), 256, 0, stream>>>(outT, g1, b1, out_lnT,
                                             nullptr, nullptr, nullptr, nullptr,
                                             nullptr, nullptr, 0);
    // 9: MLP up + GELU
    k_bmm<<<dim3(64, 16, 1), 512, 0, stream>>>(out_lnT, Wm1, b_mlp1, hT, wf | 1,
                                               nullptr, nullptr, nullptr, nullptr, 0,
                                               nullptr, nullptr, nullptr, nullptr, 0,
                                               nullptr, nullptr, MLPD, CDIM);
    // 10: MLP down + residual(out_lnT)
    k_bmm<<<dim3(64, 4, 1), 512, 0, stream>>>(hT, Wm2, b_mlp2, out2T, wf | 8,
                                              nullptr, nullptr, nullptr, nullptr, 0,
                                              nullptr, nullptr, nullptr, nullptr, 0,
                                              out_lnT, nullptr, CDIM, MLPD);
    // 11: fused LN2 + transpose -> out [256][4096]
    k_lntr<<<256, 256, 0, stream>>>(out2T, g2, b2, out);
}

// Round 3
// 212.698 us; speedup vs baseline: 1.0709x; 1.0709x over previous
//
#include <hip/hip_runtime.h>
#include <hip/hip_bf16.h>
#include <math.h>

constexpr int NTOK = 4096;
constexpr int CDIM = 256;
constexpr int MLPD = 1024;
constexpr float EPS_LN = 1e-5f;

typedef __attribute__((ext_vector_type(8))) short bf16x8;
typedef __attribute__((ext_vector_type(4))) float floatx4;
typedef __attribute__((ext_vector_type(16))) float f32x16;
typedef unsigned short u16;
typedef unsigned int u32;

__device__ __forceinline__ u16 f2bf(float x) {
    union { float f; u32 u; } v; v.f = x;
    u32 r = v.u + 0x7fff + ((v.u >> 16) & 1);
    return (u16)(r >> 16);
}
__device__ __forceinline__ float bf2f(u16 u) {
    union { u32 i; float f; } v; v.i = ((u32)u) << 16; return v.f;
}
__device__ __forceinline__ u32 pkbf(float a, float b) {
    __hip_bfloat162 h = __float22bfloat162_rn(make_float2(a, b));
    union { __hip_bfloat162 h; u32 u; } v; v.h = h; return v.u;
}
__device__ __forceinline__ float gelu_exact(float x) {
    return 0.5f * x * (1.0f + erff(x * 0.70710678118654752f));
}

// ---------------- prep: [0,512) transpose rgb/dpt; [512,768) conv3x3; rest W->bf16
__global__ __launch_bounds__(256) void k_prep(const float* __restrict__ rgb,
                                              float* __restrict__ rgbT,
                                              const float* __restrict__ dpt,
                                              float* __restrict__ dptT,
                                              const float* __restrict__ xdpt,
                                              const float* __restrict__ w3,
                                              const float* __restrict__ b3,
                                              u16* __restrict__ y,
                                              const float* __restrict__ wq,
                                              const float* __restrict__ wk,
                                              const float* __restrict__ wv,
                                              const float* __restrict__ wo,
                                              const float* __restrict__ wde2,
                                              const float* __restrict__ wm1,
                                              const float* __restrict__ wm2,
                                              u16* __restrict__ arena) {
    int blk = blockIdx.x;
    int t = threadIdx.x;
    if (blk < 512) {
        const float* in = (blk < 256) ? rgb : dpt;
        float* out = (blk < 256) ? rgbT : dptT;
        int tb = blk & 255;
        int c0 = (tb & 63) * 64, r0 = (tb >> 6) * 64;
        __shared__ float T[64][65];
        int rr = t >> 4, cc = (t & 15) * 4;
#pragma unroll
        for (int i = 0; i < 4; ++i) {
            int row = i * 16 + rr;
            float4 v = *(const float4*)(in + (size_t)(r0 + row) * NTOK + c0 + cc);
            T[row][cc] = v.x; T[row][cc + 1] = v.y; T[row][cc + 2] = v.z; T[row][cc + 3] = v.w;
        }
        __syncthreads();
#pragma unroll
        for (int i = 0; i < 4; ++i) {
            int a = i * 16 + rr;
            float4 v;
            v.x = T[cc][a]; v.y = T[cc + 1][a]; v.z = T[cc + 2][a]; v.w = T[cc + 3][a];
            *(float4*)(out + (size_t)(c0 + a) * CDIM + r0 + cc) = v;
        }
    } else if (blk < 768) {
        __shared__ float nb[3][18];
        int n0 = (blk - 512) * 16;
        int yy = n0 >> 6, x0 = n0 & 63;
        if (t < 54) {
            int r = t / 18, cc = t % 18;
            int sy = yy - 1 + r, sx = x0 - 1 + cc;
            float v = 0.f;
            if (sy >= 0 && sy < 64 && sx >= 0 && sx < 64) {
                int r0 = 16 * sy + 7, c0 = 16 * sx + 7;
                v = 0.25f * (xdpt[r0 * 1024 + c0] + xdpt[r0 * 1024 + c0 + 1] +
                             xdpt[(r0 + 1) * 1024 + c0] + xdpt[(r0 + 1) * 1024 + c0 + 1]);
            }
            nb[r][cc] = v;
        }
        __syncthreads();
        float wv9[9];
#pragma unroll
        for (int i = 0; i < 9; ++i) wv9[i] = w3[t * 9 + i];
        float bb = b3[t];
#pragma unroll
        for (int k = 0; k < 16; ++k) {
            float acc = bb;
#pragma unroll
            for (int r = 0; r < 3; ++r)
#pragma unroll
                for (int kx = 0; kx < 3; ++kx) acc += wv9[r * 3 + kx] * nb[r][k + kx];
            y[(size_t)(n0 + k) * CDIM + t] = f2bf(fmaxf(acc, 0.f));
        }
    } else {
        int e0 = (blk - 768) * 1024 + t * 4;
        const float* src; int off;
        if (e0 < 65536)       { src = wq;   off = 0; }
        else if (e0 < 131072) { src = wk;   off = 65536; }
        else if (e0 < 196608) { src = wv;   off = 131072; }
        else if (e0 < 262144) { src = wo;   off = 196608; }
        else if (e0 < 327680) { src = wde2; off = 262144; }
        else if (e0 < 589824) { src = wm1;  off = 327680; }
        else                  { src = wm2;  off = 589824; }
        float4 v = *(const float4*)(src + (e0 - off));
        uint2 o; o.x = pkbf(v.x, v.y); o.y = pkbf(v.z, v.w);
        *(uint2*)(arena + e0) = o;
    }
}

// ---------------- token-major LayerNorm (dual-set via blockIdx.y) ----------------
__global__ __launch_bounds__(256) void k_lnT(const void* __restrict__ xA,
                                             const float* __restrict__ gA,
                                             const float* __restrict__ bA,
                                             void* __restrict__ yA,
                                             const void* __restrict__ xB,
                                             const float* __restrict__ gB,
                                             const float* __restrict__ bB,
                                             void* __restrict__ yB,
                                             const u16* __restrict__ pe,
                                             const float* __restrict__ pos,
                                             int xf32) {
    const void* x; const float* g; const float* bb; void* y;
    if (blockIdx.y == 0) { x = xA; g = gA; bb = bA; y = yA; }
    else                 { x = xB; g = gB; bb = bB; y = yB; }
    int n = blockIdx.x * 4 + (threadIdx.x >> 6);
    int lane = threadIdx.x & 63;
    int c = lane * 4;
    float4 xv;
    if (xf32) {
        xv = *((const float4*)x + (size_t)n * 64 + lane);
    } else {
        ushort4 u = *((const ushort4*)x + (size_t)n * 64 + lane);
        xv = make_float4(bf2f(u.x), bf2f(u.y), bf2f(u.z), bf2f(u.w));
    }
    float s = xv.x + xv.y + xv.z + xv.w;
    float s2 = xv.x * xv.x + xv.y * xv.y + xv.z * xv.z + xv.w * xv.w;
#pragma unroll
    for (int off = 1; off < 64; off <<= 1) {
        s += __shfl_xor(s, off, 64);
        s2 += __shfl_xor(s2, off, 64);
    }
    float mu = s * (1.0f / 256.0f);
    float var = s2 * (1.0f / 256.0f) - mu * mu;
    float rsd = rsqrtf(var + EPS_LN);
    float4 g4 = *(const float4*)(g + c);
    float4 b4 = *(const float4*)(bb + c);
    float4 o;
    o.x = (xv.x - mu) * rsd * g4.x + b4.x;
    o.y = (xv.y - mu) * rsd * g4.y + b4.y;
    o.z = (xv.z - mu) * rsd * g4.z + b4.z;
    o.w = (xv.w - mu) * rsd * g4.w + b4.w;
    if (pe) {
        float4 p4 = *(const float4*)(pos + c);
        ushort4 pu = *((const ushort4*)pe + (size_t)n * 64 + lane);
        o.x += p4.x + bf2f(pu.x);
        o.y += p4.y + bf2f(pu.y);
        o.z += p4.z + bf2f(pu.z);
        o.w += p4.w + bf2f(pu.w);
    }
    ushort4 ou;
    ou.x = f2bf(o.x); ou.y = f2bf(o.y); ou.z = f2bf(o.z); ou.w = f2bf(o.w);
    *((ushort4*)y + (size_t)n * 64 + lane) = ou;
}

// ---------------- bf16 MFMA GEMM, 512 threads, in-block split-K ------------------
// flags: 1 GELU | 2 swap-out [m][4096] | 4 res f32 [N][M] | 8 res bf16 [N][M]
//      | 16 smul=log2e/scl | 32 W bf16 | 64 head-major out [m>>5][tok][m&31]
#define LDB 72
__global__ __launch_bounds__(512) void k_bmm(const u16* __restrict__ X0, const void* __restrict__ W0,
                                             const float* __restrict__ B0, void* __restrict__ Y0, int f0,
                                             const u16* __restrict__ X1, const void* __restrict__ W1,
                                             const float* __restrict__ B1, void* __restrict__ Y1, int f1,
                                             const u16* __restrict__ X2, const void* __restrict__ W2,
                                             const float* __restrict__ B2, void* __restrict__ Y2, int f2,
                                             const void* __restrict__ res, const float* __restrict__ scl,
                                             int M, int K) {
    const u16* X; const void* Wp; const float* bias; void* Yp; int flags;
    if (blockIdx.z == 0)      { X = X0; Wp = W0; bias = B0; Yp = Y0; flags = f0; }
    else if (blockIdx.z == 1) { X = X1; Wp = W1; bias = B1; Yp = Y1; flags = f1; }
    else                      { X = X2; Wp = W2; bias = B2; Yp = Y2; flags = f2; }
    __shared__ u16 Xs[2][64 * LDB];
    __shared__ u16 Ws[2][64 * LDB];
    float* Cred = (float*)&Xs[0][0];

    int tid = threadIdx.x;
    int kg = tid >> 8;
    int t = tid & 255;
    int wid = t >> 6, lane = t & 63;
    int lo16 = lane & 15, quad = lane >> 4;
    int wy = wid & 1, wx = wid >> 1;
    int n0 = blockIdx.x * 64, m0 = blockIdx.y * 64;
    int srow = t >> 2, sseg = t & 3;
    int Khalf = K >> 1;
    int kbase = kg * Khalf;

    floatx4 acc[2][2];
#pragma unroll
    for (int i = 0; i < 2; ++i)
#pragma unroll
        for (int j = 0; j < 2; ++j) acc[i][j] = floatx4{0.f, 0.f, 0.f, 0.f};

    for (int k0 = 0; k0 < Khalf; k0 += 64) {
        int kk = kbase + k0;
        const u16* xp = X + (size_t)(n0 + srow) * K + kk + sseg * 16;
        uint4 xr0 = *(const uint4*)xp;
        uint4 xr1 = *(const uint4*)(xp + 8);
        uint4 wb0, wb1;
        if (flags & 32) {
            const u16* wp = (const u16*)Wp + (size_t)(m0 + srow) * K + kk + sseg * 16;
            wb0 = *(const uint4*)wp;
            wb1 = *(const uint4*)(wp + 8);
        } else {
            const float* wp = (const float*)Wp + (size_t)(m0 + srow) * K + kk + sseg * 16;
            float4 w0 = *(const float4*)wp;
            float4 w1 = *(const float4*)(wp + 4);
            float4 w2 = *(const float4*)(wp + 8);
            float4 w3 = *(const float4*)(wp + 12);
            wb0.x = pkbf(w0.x, w0.y); wb0.y = pkbf(w0.z, w0.w);
            wb0.z = pkbf(w1.x, w1.y); wb0.w = pkbf(w1.z, w1.w);
            wb1.x = pkbf(w2.x, w2.y); wb1.y = pkbf(w2.z, w2.w);
            wb1.z = pkbf(w3.x, w3.y); wb1.w = pkbf(w3.z, w3.w);
        }
        __syncthreads();
        *(uint4*)&Xs[kg][srow * LDB + sseg * 16] = xr0;
        *(uint4*)&Xs[kg][srow * LDB + sseg * 16 + 8] = xr1;
        *(uint4*)&Ws[kg][srow * LDB + sseg * 16] = wb0;
        *(uint4*)&Ws[kg][srow * LDB + sseg * 16 + 8] = wb1;
        __syncthreads();

        const u16* As = (flags & 2) ? &Ws[kg][0] : &Xs[kg][0];
        const u16* Bs = (flags & 2) ? &Xs[kg][0] : &Ws[kg][0];
#pragma unroll
        for (int h = 0; h < 2; ++h) {
            int ko = h * 32 + quad * 8;
            bf16x8 a0 = *(const bf16x8*)&As[(wy * 32 + lo16) * LDB + ko];
            bf16x8 a1 = *(const bf16x8*)&As[(wy * 32 + 16 + lo16) * LDB + ko];
            bf16x8 b0 = *(const bf16x8*)&Bs[(wx * 32 + lo16) * LDB + ko];
            bf16x8 b1 = *(const bf16x8*)&Bs[(wx * 32 + 16 + lo16) * LDB + ko];
            acc[0][0] = __builtin_amdgcn_mfma_f32_16x16x32_bf16(a0, b0, acc[0][0], 0, 0, 0);
            acc[0][1] = __builtin_amdgcn_mfma_f32_16x16x32_bf16(a0, b1, acc[0][1], 0, 0, 0);
            acc[1][0] = __builtin_amdgcn_mfma_f32_16x16x32_bf16(a1, b0, acc[1][0], 0, 0, 0);
            acc[1][1] = __builtin_amdgcn_mfma_f32_16x16x32_bf16(a1, b1, acc[1][1], 0, 0, 0);
        }
    }

    __syncthreads();
    if (kg == 1) {
        float* c = &Cred[t * 17];
#pragma unroll
        for (int i = 0; i < 2; ++i)
#pragma unroll
            for (int j = 0; j < 2; ++j)
#pragma unroll
                for (int r = 0; r < 4; ++r) c[(i * 2 + j) * 4 + r] = acc[i][j][r];
    }
    __syncthreads();
    if (kg == 1) return;
    {
        const float* c = &Cred[t * 17];
#pragma unroll
        for (int i = 0; i < 2; ++i)
#pragma unroll
            for (int j = 0; j < 2; ++j)
#pragma unroll
                for (int r = 0; r < 4; ++r) acc[i][j][r] += c[(i * 2 + j) * 4 + r];
    }

    u16* Y = (u16*)Yp;
    if (flags & 2) {
#pragma unroll
        for (int i = 0; i < 2; ++i)
#pragma unroll
            for (int r = 0; r < 4; ++r) {
                int ch = m0 + wy * 32 + i * 16 + quad * 4 + r;
                float bb = bias[ch];
#pragma unroll
                for (int j = 0; j < 2; ++j) {
                    int tok = n0 + wx * 32 + j * 16 + lo16;
                    Y[(size_t)ch * NTOK + tok] = f2bf(acc[i][j][r] + bb);
                }
            }
    } else {
        float smul = (flags & 16) ? 1.4426950408889634f / scl[0] : 1.0f;
        float bj0 = bias[m0 + wx * 32 + lo16];
        float bj1 = bias[m0 + wx * 32 + 16 + lo16];
        const float* rf = (const float*)res;
        const u16* rb = (const u16*)res;
#pragma unroll
        for (int i = 0; i < 2; ++i)
#pragma unroll
            for (int j = 0; j < 2; ++j) {
                int ch = m0 + wx * 32 + j * 16 + lo16;
                float bb = j ? bj1 : bj0;
#pragma unroll
                for (int r = 0; r < 4; ++r) {
                    int tok = n0 + wy * 32 + i * 16 + quad * 4 + r;
                    float v = (acc[i][j][r] + bb) * smul;
                    if (flags & 1) v = gelu_exact(v);
                    if (flags & 4) v += rf[(size_t)tok * M + ch];
                    if (flags & 8) v += bf2f(rb[(size_t)tok * M + ch]);
                    if (flags & 64)
                        Y[((size_t)(ch >> 5) * NTOK + tok) * 32 + (ch & 31)] = f2bf(v);
                    else
                        Y[(size_t)tok * M + ch] = f2bf(v);
                }
            }
    }
}

// ---------------- split-K flash attention, 32x32 MFMA, register P ----------------
// grid (32, 8, split): block = 128 queries (4 waves x 32q) x (niter*64) keys.
// K/V tile staged in DOUBLE-BUFFERED LDS -> ONE barrier per 64-key tile; next
// tile's global loads issued right after the barrier (overlap compute). Softmax
// in registers (swapped QK^T); PV A-frags rebuilt via one cross-half shuffle.
#define LDK 40
#define LDV 72
__global__ __launch_bounds__(256) void k_fattn(const u16* __restrict__ Qh,
                                               const u16* __restrict__ Kh,
                                               const u16* __restrict__ Vc,
                                               u16* __restrict__ Op,
                                               float* __restrict__ Lp,
                                               int niter) {
    __shared__ u16 Kt[2][64 * LDK];        // 10240 B
    __shared__ u16 Vt[2][32 * LDV];        // 9216 B  (19.4 KB total, 8 blocks/CU)

    int h = blockIdx.y;
    int q0 = blockIdx.x * 128;
    int sp = blockIdx.z;
    int tid = threadIdx.x;
    int wid = tid >> 6, lane = tid & 63;
    int ql = lane & 31, hi = lane >> 5;
    int qtok = q0 + wid * 32 + ql;

    // stationary Q as B-operand: col=q=ql, k=d (two 16-wide d-halves)
    const u16* qp = Qh + ((size_t)h * NTOK + qtok) * 32 + hi * 8;
    bf16x8 bq0 = *(const bf16x8*)(qp);
    bf16x8 bq1 = *(const bf16x8*)(qp + 16);

    int krow = tid >> 2, kseg = tid & 3;   // 64 rows x 4 segs of 16B
    int vrow = tid >> 3, vseg = tid & 7;   // 32 rows x 8 segs of 16B
    int kbase = sp * (niter * 64);

    f32x16 oacc = {0.f, 0.f, 0.f, 0.f, 0.f, 0.f, 0.f, 0.f,
                   0.f, 0.f, 0.f, 0.f, 0.f, 0.f, 0.f, 0.f};
    float l = 0.f;

    uint4 kreg = *(const uint4*)(Kh + ((size_t)h * NTOK + kbase + krow) * 32 + kseg * 8);
    uint4 vreg = *(const uint4*)(Vc + (size_t)(h * 32 + vrow) * NTOK + kbase + vseg * 8);

    for (int kt = 0; kt < niter; ++kt) {
        int cb = kt & 1;
        *(uint4*)&Kt[cb][krow * LDK + kseg * 8] = kreg;
        *(uint4*)&Vt[cb][vrow * LDV + vseg * 8] = vreg;
        __syncthreads();                   // single barrier per tile (dbuf)
        if (kt + 1 < niter) {              // issue next tile early, overlap compute
            int kn = kbase + (kt + 1) * 64;
            kreg = *(const uint4*)(Kh + ((size_t)h * NTOK + kn + krow) * 32 + kseg * 8);
            vreg = *(const uint4*)(Vc + (size_t)(h * 32 + vrow) * NTOK + kn + vseg * 8);
        }

#pragma unroll
        for (int sub = 0; sub < 2; ++sub) {
            // S^T[key][q] over 32 keys, d=32 via two K=16 MFMAs
            f32x16 s = {0.f, 0.f, 0.f, 0.f, 0.f, 0.f, 0.f, 0.f,
                        0.f, 0.f, 0.f, 0.f, 0.f, 0.f, 0.f, 0.f};
            bf16x8 ak0 = *(const bf16x8*)&Kt[cb][(sub * 32 + ql) * LDK + hi * 8];
            bf16x8 ak1 = *(const bf16x8*)&Kt[cb][(sub * 32 + ql) * LDK + 16 + hi * 8];
            s = __builtin_amdgcn_mfma_f32_32x32x16_bf16(ak0, bq0, s, 0, 0, 0);
            s = __builtin_amdgcn_mfma_f32_32x32x16_bf16(ak1, bq1, s, 0, 0, 0);
            // p = exp2(s) (scores O(1), no max); pack pairs of adjacent keys:
            // u[t] = P[q][keys (2t&3)+8*(t>>1)+4*hi .. +1]
            u32 u[8], px[8];
#pragma unroll
            for (int t = 0; t < 8; ++t) {
                float pa = __builtin_amdgcn_exp2f(s[2 * t]);
                float pb = __builtin_amdgcn_exp2f(s[2 * t + 1]);
                l += pa + pb;
                u[t] = pkbf(pa, pb);
            }
#pragma unroll
            for (int t = 0; t < 8; ++t) px[t] = (u32)__shfl_xor((int)u[t], 32, 64);
            // rebuild PV A-fragments (row=q, k=key): m=0 -> keys sub*32+0..15,
            // m=1 -> keys sub*32+16..31; slots verified against acc layout.
            uint4 wa, wb;
            wa.x = hi ? px[2] : u[0];
            wa.y = hi ? px[3] : u[1];
            wa.z = hi ? u[2] : px[0];
            wa.w = hi ? u[3] : px[1];
            wb.x = hi ? px[6] : u[4];
            wb.y = hi ? px[7] : u[5];
            wb.z = hi ? u[6] : px[4];
            wb.w = hi ? u[7] : px[5];
            union { uint4 q; bf16x8 v; } pa0, pa1;
            pa0.q = wa; pa1.q = wb;
            // B-operand V[key][d] from d-major Vt rows: col=d=ql, k=key
            bf16x8 bv0 = *(const bf16x8*)&Vt[cb][ql * LDV + sub * 32 + hi * 8];
            bf16x8 bv1 = *(const bf16x8*)&Vt[cb][ql * LDV + sub * 32 + 16 + hi * 8];
            oacc = __builtin_amdgcn_mfma_f32_32x32x16_bf16(pa0.v, bv0, oacc, 0, 0, 0);
            oacc = __builtin_amdgcn_mfma_f32_32x32x16_bf16(pa1.v, bv1, oacc, 0, 0, 0);
        }
    }

    // l for q=ql: this lane summed its hi-half of keys; combine halves
    l += __shfl_xor(l, 32, 64);

    // O partial: rows q = (r&3)+8*(r>>2)+4*hi, col d = ql
    size_t obase = ((size_t)(sp * 8 + h) * NTOK + q0 + wid * 32) * 32 + ql;
#pragma unroll
    for (int r = 0; r < 16; ++r) {
        int qrow = (r & 3) + 8 * (r >> 2) + 4 * hi;
        Op[obase + (size_t)qrow * 32] = f2bf(oacc[r]);
    }
    if (hi == 0) Lp[(size_t)(sp * 8 + h) * NTOK + qtok] = l;
}

// ---------------- combine split partials -> fused bf16 [tok][256] ----------------
__global__ __launch_bounds__(256) void k_comb(const u16* __restrict__ Op,
                                              const float* __restrict__ Lp,
                                              u16* __restrict__ fused,
                                              int split) {
    int n = blockIdx.x * 4 + (threadIdx.x >> 6);
    int lane = threadIdx.x & 63;
    int c = lane * 4;
    int h = c >> 5, d = c & 31;
    float4 o = {0.f, 0.f, 0.f, 0.f};
    float l = 0.f;
    for (int s = 0; s < split; ++s) {
        size_t base = ((size_t)(s * 8 + h) * NTOK + n) * 32 + d;
        uint2 u = *(const uint2*)(Op + base);
        o.x += bf2f((u16)(u.x & 0xffff)); o.y += bf2f((u16)(u.x >> 16));
        o.z += bf2f((u16)(u.y & 0xffff)); o.w += bf2f((u16)(u.y >> 16));
        l += Lp[(size_t)(s * 8 + h) * NTOK + n];
    }
    float inv = 1.0f / l;
    uint2 w;
    w.x = pkbf(o.x * inv, o.y * inv);
    w.y = pkbf(o.z * inv, o.w * inv);
    *(uint2*)(fused + (size_t)n * CDIM + c) = w;
}

// ---------------- fused LN2 + transpose: out2T bf16 [4096][256] -> out f32 [256][4096]
__global__ __launch_bounds__(256) void k_lntr(const u16* __restrict__ x,
                                              const float* __restrict__ g,
                                              const float* __restrict__ b,
                                              float* __restrict__ out) {
    __shared__ float T[16][260];
    int n0 = blockIdx.x * 16;
    int t = threadIdx.x;
    int tk = t >> 4, seg = t & 15;
    float v[16];
    {
        const u16* p = x + (size_t)(n0 + tk) * CDIM + seg * 16;
        uint4 a = *(const uint4*)p;
        uint4 bq = *(const uint4*)(p + 8);
        u32 uu[8] = {a.x, a.y, a.z, a.w, bq.x, bq.y, bq.z, bq.w};
#pragma unroll
        for (int i = 0; i < 8; ++i) {
            v[2 * i] = bf2f((u16)(uu[i] & 0xffff));
            v[2 * i + 1] = bf2f((u16)(uu[i] >> 16));
        }
    }
    float s = 0.f, s2 = 0.f;
#pragma unroll
    for (int i = 0; i < 16; ++i) { s += v[i]; s2 += v[i] * v[i]; }
#pragma unroll
    for (int off = 1; off < 16; off <<= 1) {
        s += __shfl_xor(s, off, 64);
        s2 += __shfl_xor(s2, off, 64);
    }
    float mu = s * (1.0f / 256.0f);
    float var = s2 * (1.0f / 256.0f) - mu * mu;
    float rsd = rsqrtf(var + EPS_LN);
#pragma unroll
    for (int i = 0; i < 16; ++i) {
        int c = seg * 16 + i;
        T[tk][c] = (v[i] - mu) * rsd * g[c] + b[c];
    }
    __syncthreads();
    int c = t;
    float o[16];
#pragma unroll
    for (int j = 0; j < 16; ++j) o[j] = T[j][c];
    float* dst = out + (size_t)c * NTOK + n0;
#pragma unroll
    for (int j = 0; j < 4; ++j) {
        float4 w = {o[4 * j], o[4 * j + 1], o[4 * j + 2], o[4 * j + 3]};
        *(float4*)(dst + 4 * j) = w;
    }
}

// ------------------------------------------------------------------------------
extern "C" void kernel_launch(void* const* d_in, const int* in_sizes, int n_in,
                              void* d_out, int out_size, void* d_ws, size_t ws_size,
                              hipStream_t stream) {
    const float* rgb    = (const float*)d_in[0];
    const float* dpt    = (const float*)d_in[1];
    const float* x_dpt  = (const float*)d_in[2];
    const float* wq     = (const float*)d_in[3];
    const float* bq     = (const float*)d_in[4];
    const float* wk     = (const float*)d_in[5];
    const float* bk     = (const float*)d_in[6];
    const float* wv     = (const float*)d_in[7];
    const float* bv     = (const float*)d_in[8];
    const float* wo     = (const float*)d_in[9];
    const float* bo     = (const float*)d_in[10];
    const float* g_rgb  = (const float*)d_in[11];
    const float* b_rgb  = (const float*)d_in[12];
    const float* g_dpt  = (const float*)d_in[13];
    const float* b_dpt  = (const float*)d_in[14];
    const float* g1     = (const float*)d_in[15];
    const float* b1     = (const float*)d_in[16];
    const float* g2     = (const float*)d_in[17];
    const float* b2     = (const float*)d_in[18];
    const float* w_mlp1 = (const float*)d_in[19];
    const float* b_mlp1 = (const float*)d_in[20];
    const float* w_mlp2 = (const float*)d_in[21];
    const float* b_mlp2 = (const float*)d_in[22];
    const float* w_de1  = (const float*)d_in[23];
    const float* b_de1  = (const float*)d_in[24];
    const float* w_de2  = (const float*)d_in[25];
    const float* b_de2  = (const float*)d_in[26];
    const float* pos    = (const float*)d_in[27];
    const float* scale  = (const float*)d_in[28];
    float* out = (float*)d_out;

    char* base = (char*)d_ws;
    const size_t MB = 1u << 20;
    float* rgbT    = (float*)(base + 0 * MB);
    float* dptT    = (float*)(base + 4 * MB);
    u16*   outT    = (u16*)(base + 4 * MB);
    float* Lp4     = (float*)(base + 6 * MB);    // fattn..comb (512 KB, split=4 path)
    u16*   out_lnT = (u16*)(base + 6 * MB);      // ln1..mlp2 (after comb)
    u16*   relu3T  = (u16*)(base + 8 * MB);      // prep..peGEMM
    u16*   Op4     = (u16*)(base + 8 * MB);      // fattn..comb (8 MB, split=4 path)
    u16*   hT      = (u16*)(base + 8 * MB);      // mlp1..mlp2 (after comb)
    u16*   peT     = (u16*)(base + 10 * MB);     // peGEMM..LN
    u16*   aqT     = (u16*)(base + 12 * MB);     // LN..QKV
    u16*   akvT    = (u16*)(base + 14 * MB);     // LN..QKV
    u16*   Qhm     = (u16*)(base + 16 * MB);     // QKV..fattn
    u16*   out2T   = (u16*)(base + 16 * MB);     // mlp2..ln2
    u16*   Khm     = (u16*)(base + 18 * MB);
    u16*   Vcm     = (u16*)(base + 20 * MB);
    u16*   fusedT  = (u16*)(base + 22 * MB);     // comb..wo
    u16*   arena   = (u16*)(base + 24 * MB);     // bf16 weights

    bool aw = ws_size >= 26 * MB;
    int wf = aw ? 32 : 0;
    const void* Wq  = aw ? (const void*)(arena + 0)      : (const void*)wq;
    const void* Wk  = aw ? (const void*)(arena + 65536)  : (const void*)wk;
    const void* Wv  = aw ? (const void*)(arena + 131072) : (const void*)wv;
    const void* Wo  = aw ? (const void*)(arena + 196608) : (const void*)wo;
    const void* Wd2 = aw ? (const void*)(arena + 262144) : (const void*)w_de2;
    const void* Wm1 = aw ? (const void*)(arena + 327680) : (const void*)w_mlp1;
    const void* Wm2 = aw ? (const void*)(arena + 589824) : (const void*)w_mlp2;

    // split-K width for attention: 8 if workspace allows (Op 16MB + Lp 1MB high),
    // else fall back to the split=4 packed layout.
    int split = (ws_size >= 68 * MB) ? 8 : 4;
    u16*   Op = (split == 8) ? (u16*)(base + 32 * MB) : Op4;
    float* Lp = (split == 8) ? (float*)(base + 48 * MB) : Lp4;

    // 1: transposes + downsample/conv3x3 + weight conversion
    k_prep<<<aw ? 512 + 256 + 832 : 512 + 256, 256, 0, stream>>>(
        rgb, rgbT, dpt, dptT, x_dpt, w_de1, b_de1, relu3T,
        wq, wk, wv, wo, w_de2, w_mlp1, w_mlp2, arena);
    // 2: pe = 1x1(relu3)
    k_bmm<<<dim3(64, 4, 1), 512, 0, stream>>>(relu3T, Wd2, b_de2, peT, wf,
                                              nullptr, nullptr, nullptr, nullptr, 0,
                                              nullptr, nullptr, nullptr, nullptr, 0,
                                              nullptr, nullptr, CDIM, CDIM);
    // 3: both LayerNorms (+pos+pe)
    k_lnT<<<dim3(1024, 2), 256, 0, stream>>>(rgbT, g_rgb, b_rgb, aqT,
                                             dptT, g_dpt, b_dpt, akvT,
                                             peT, pos, 1);
    // 4: QKV (q scaled+head-major, k head-major, v channel-major)
    k_bmm<<<dim3(64, 4, 3), 512, 0, stream>>>(aqT, Wq, bq, Qhm, wf | 16 | 64,
                                              akvT, Wk, bk, Khm, wf | 64,
                                              akvT, Wv, bv, Vcm, wf | 2,
                                              nullptr, scale, CDIM, CDIM);
    // 5: split-K flash attention (dbuf LDS, 1 barrier/tile, register P)
    k_fattn<<<dim3(32, 8, split), 256, 0, stream>>>(Qhm, Khm, Vcm, Op, Lp,
                                                    NTOK / split / 64);
    // 6: combine partials
    k_comb<<<1024, 256, 0, stream>>>(Op, Lp, fusedT, split);
    // 7: output projection + residual(rgbT)
    k_bmm<<<dim3(64, 4, 1), 512, 0, stream>>>(fusedT, Wo, bo, outT, wf | 4,
                                              nullptr, nullptr, nullptr, nullptr, 0,
                                              nullptr, nullptr, nullptr, nullptr, 0,
                                              rgbT, nullptr, CDIM, CDIM);
    // 8: LN1
    k_lnT<<<dim3(1024, 1), 256, 0, stream>>>(outT, g1, b1, out_lnT,
                                             nullptr, nullptr, nullptr, nullptr,
                                             nullptr, nullptr, 0);
    // 9: MLP up + GELU
    k_bmm<<<dim3(64, 16, 1), 512, 0, stream>>>(out_lnT, Wm1, b_mlp1, hT, wf | 1,
                                               nullptr, nullptr, nullptr, nullptr, 0,
                                               nullptr, nullptr, nullptr, nullptr, 0,
                                               nullptr, nullptr, MLPD, CDIM);
    // 10: MLP down + residual(out_lnT)
    k_bmm<<<dim3(64, 4, 1), 512, 0, stream>>>(hT, Wm2, b_mlp2, out2T, wf | 8,
                                              nullptr, nullptr, nullptr, nullptr, 0,
                                              nullptr, nullptr, nullptr, nullptr, 0,
                                              out_lnT, nullptr, CDIM, MLPD);
    // 11: fused LN2 + transpose -> out [256][4096]
    k_lntr<<<256, 256, 0, stream>>>(out2T, g2, b2, out);
}

// Round 4
// 210.105 us; speedup vs baseline: 1.0841x; 1.0123x over previous
//
#include <hip/hip_runtime.h>
#include <hip/hip_bf16.h>
#include <math.h>

constexpr int NTOK = 4096;
constexpr int CDIM = 256;
constexpr int MLPD = 1024;
constexpr float EPS_LN = 1e-5f;

typedef __attribute__((ext_vector_type(8))) short bf16x8;
typedef __attribute__((ext_vector_type(4))) float floatx4;
typedef __attribute__((ext_vector_type(16))) float f32x16;
typedef __attribute__((ext_vector_type(2))) unsigned int u32x2;
typedef unsigned short u16;
typedef unsigned int u32;

#if defined(__has_builtin)
#if __has_builtin(__builtin_amdgcn_permlane32_swap)
#define HAVE_PLSWAP 1
#endif
#endif

__device__ __forceinline__ u16 f2bf(float x) {
    union { float f; u32 u; } v; v.f = x;
    u32 r = v.u + 0x7fff + ((v.u >> 16) & 1);
    return (u16)(r >> 16);
}
__device__ __forceinline__ float bf2f(u16 u) {
    union { u32 i; float f; } v; v.i = ((u32)u) << 16; return v.f;
}
__device__ __forceinline__ u32 pkbf(float a, float b) {
    __hip_bfloat162 h = __float22bfloat162_rn(make_float2(a, b));
    union { __hip_bfloat162 h; u32 u; } v; v.h = h; return v.u;
}
__device__ __forceinline__ float gelu_exact(float x) {
    return 0.5f * x * (1.0f + erff(x * 0.70710678118654752f));
}

// ---------------- prep: [0,512) transpose rgb/dpt; [512,768) conv3x3; rest W->bf16
__global__ __launch_bounds__(256) void k_prep(const float* __restrict__ rgb,
                                              float* __restrict__ rgbT,
                                              const float* __restrict__ dpt,
                                              float* __restrict__ dptT,
                                              const float* __restrict__ xdpt,
                                              const float* __restrict__ w3,
                                              const float* __restrict__ b3,
                                              u16* __restrict__ y,
                                              const float* __restrict__ wq,
                                              const float* __restrict__ wk,
                                              const float* __restrict__ wv,
                                              const float* __restrict__ wo,
                                              const float* __restrict__ wde2,
                                              const float* __restrict__ wm1,
                                              const float* __restrict__ wm2,
                                              u16* __restrict__ arena) {
    int blk = blockIdx.x;
    int t = threadIdx.x;
    if (blk < 512) {
        const float* in = (blk < 256) ? rgb : dpt;
        float* out = (blk < 256) ? rgbT : dptT;
        int tb = blk & 255;
        int c0 = (tb & 63) * 64, r0 = (tb >> 6) * 64;
        __shared__ float T[64][65];
        int rr = t >> 4, cc = (t & 15) * 4;
#pragma unroll
        for (int i = 0; i < 4; ++i) {
            int row = i * 16 + rr;
            float4 v = *(const float4*)(in + (size_t)(r0 + row) * NTOK + c0 + cc);
            T[row][cc] = v.x; T[row][cc + 1] = v.y; T[row][cc + 2] = v.z; T[row][cc + 3] = v.w;
        }
        __syncthreads();
#pragma unroll
        for (int i = 0; i < 4; ++i) {
            int a = i * 16 + rr;
            float4 v;
            v.x = T[cc][a]; v.y = T[cc + 1][a]; v.z = T[cc + 2][a]; v.w = T[cc + 3][a];
            *(float4*)(out + (size_t)(c0 + a) * CDIM + r0 + cc) = v;
        }
    } else if (blk < 768) {
        __shared__ float nb[3][18];
        int n0 = (blk - 512) * 16;
        int yy = n0 >> 6, x0 = n0 & 63;
        if (t < 54) {
            int r = t / 18, cc = t % 18;
            int sy = yy - 1 + r, sx = x0 - 1 + cc;
            float v = 0.f;
            if (sy >= 0 && sy < 64 && sx >= 0 && sx < 64) {
                int r0 = 16 * sy + 7, c0 = 16 * sx + 7;
                v = 0.25f * (xdpt[r0 * 1024 + c0] + xdpt[r0 * 1024 + c0 + 1] +
                             xdpt[(r0 + 1) * 1024 + c0] + xdpt[(r0 + 1) * 1024 + c0 + 1]);
            }
            nb[r][cc] = v;
        }
        __syncthreads();
        float wv9[9];
#pragma unroll
        for (int i = 0; i < 9; ++i) wv9[i] = w3[t * 9 + i];
        float bb = b3[t];
#pragma unroll
        for (int k = 0; k < 16; ++k) {
            float acc = bb;
#pragma unroll
            for (int r = 0; r < 3; ++r)
#pragma unroll
                for (int kx = 0; kx < 3; ++kx) acc += wv9[r * 3 + kx] * nb[r][k + kx];
            y[(size_t)(n0 + k) * CDIM + t] = f2bf(fmaxf(acc, 0.f));
        }
    } else {
        int e0 = (blk - 768) * 1024 + t * 4;
        const float* src; int off;
        if (e0 < 65536)       { src = wq;   off = 0; }
        else if (e0 < 131072) { src = wk;   off = 65536; }
        else if (e0 < 196608) { src = wv;   off = 131072; }
        else if (e0 < 262144) { src = wo;   off = 196608; }
        else if (e0 < 327680) { src = wde2; off = 262144; }
        else if (e0 < 589824) { src = wm1;  off = 327680; }
        else                  { src = wm2;  off = 589824; }
        float4 v = *(const float4*)(src + (e0 - off));
        uint2 o; o.x = pkbf(v.x, v.y); o.y = pkbf(v.z, v.w);
        *(uint2*)(arena + e0) = o;
    }
}

// ---------------- token-major LayerNorm (dual-set via blockIdx.y) ----------------
__global__ __launch_bounds__(256) void k_lnT(const void* __restrict__ xA,
                                             const float* __restrict__ gA,
                                             const float* __restrict__ bA,
                                             void* __restrict__ yA,
                                             const void* __restrict__ xB,
                                             const float* __restrict__ gB,
                                             const float* __restrict__ bB,
                                             void* __restrict__ yB,
                                             const u16* __restrict__ pe,
                                             const float* __restrict__ pos,
                                             int xf32) {
    const void* x; const float* g; const float* bb; void* y;
    if (blockIdx.y == 0) { x = xA; g = gA; bb = bA; y = yA; }
    else                 { x = xB; g = gB; bb = bB; y = yB; }
    int n = blockIdx.x * 4 + (threadIdx.x >> 6);
    int lane = threadIdx.x & 63;
    int c = lane * 4;
    float4 xv;
    if (xf32) {
        xv = *((const float4*)x + (size_t)n * 64 + lane);
    } else {
        ushort4 u = *((const ushort4*)x + (size_t)n * 64 + lane);
        xv = make_float4(bf2f(u.x), bf2f(u.y), bf2f(u.z), bf2f(u.w));
    }
    float s = xv.x + xv.y + xv.z + xv.w;
    float s2 = xv.x * xv.x + xv.y * xv.y + xv.z * xv.z + xv.w * xv.w;
#pragma unroll
    for (int off = 1; off < 64; off <<= 1) {
        s += __shfl_xor(s, off, 64);
        s2 += __shfl_xor(s2, off, 64);
    }
    float mu = s * (1.0f / 256.0f);
    float var = s2 * (1.0f / 256.0f) - mu * mu;
    float rsd = rsqrtf(var + EPS_LN);
    float4 g4 = *(const float4*)(g + c);
    float4 b4 = *(const float4*)(bb + c);
    float4 o;
    o.x = (xv.x - mu) * rsd * g4.x + b4.x;
    o.y = (xv.y - mu) * rsd * g4.y + b4.y;
    o.z = (xv.z - mu) * rsd * g4.z + b4.z;
    o.w = (xv.w - mu) * rsd * g4.w + b4.w;
    if (pe) {
        float4 p4 = *(const float4*)(pos + c);
        ushort4 pu = *((const ushort4*)pe + (size_t)n * 64 + lane);
        o.x += p4.x + bf2f(pu.x);
        o.y += p4.y + bf2f(pu.y);
        o.z += p4.z + bf2f(pu.z);
        o.w += p4.w + bf2f(pu.w);
    }
    ushort4 ou;
    ou.x = f2bf(o.x); ou.y = f2bf(o.y); ou.z = f2bf(o.z); ou.w = f2bf(o.w);
    *((ushort4*)y + (size_t)n * 64 + lane) = ou;
}

// ---------------- bf16 MFMA GEMM, 512 threads, in-block split-K ------------------
// flags: 1 GELU | 2 swap-out [m][4096] | 4 res f32 [N][M] | 8 res bf16 [N][M]
//      | 16 smul=log2e/scl | 32 W bf16 | 64 head-major out [m>>5][tok][m&31]
#define LDB 72
__global__ __launch_bounds__(512) void k_bmm(const u16* __restrict__ X0, const void* __restrict__ W0,
                                             const float* __restrict__ B0, void* __restrict__ Y0, int f0,
                                             const u16* __restrict__ X1, const void* __restrict__ W1,
                                             const float* __restrict__ B1, void* __restrict__ Y1, int f1,
                                             const u16* __restrict__ X2, const void* __restrict__ W2,
                                             const float* __restrict__ B2, void* __restrict__ Y2, int f2,
                                             const void* __restrict__ res, const float* __restrict__ scl,
                                             int M, int K) {
    const u16* X; const void* Wp; const float* bias; void* Yp; int flags;
    if (blockIdx.z == 0)      { X = X0; Wp = W0; bias = B0; Yp = Y0; flags = f0; }
    else if (blockIdx.z == 1) { X = X1; Wp = W1; bias = B1; Yp = Y1; flags = f1; }
    else                      { X = X2; Wp = W2; bias = B2; Yp = Y2; flags = f2; }
    __shared__ u16 Xs[2][64 * LDB];
    __shared__ u16 Ws[2][64 * LDB];
    float* Cred = (float*)&Xs[0][0];

    int tid = threadIdx.x;
    int kg = tid >> 8;
    int t = tid & 255;
    int wid = t >> 6, lane = t & 63;
    int lo16 = lane & 15, quad = lane >> 4;
    int wy = wid & 1, wx = wid >> 1;
    int n0 = blockIdx.x * 64, m0 = blockIdx.y * 64;
    int srow = t >> 2, sseg = t & 3;
    int Khalf = K >> 1;
    int kbase = kg * Khalf;

    floatx4 acc[2][2];
#pragma unroll
    for (int i = 0; i < 2; ++i)
#pragma unroll
        for (int j = 0; j < 2; ++j) acc[i][j] = floatx4{0.f, 0.f, 0.f, 0.f};

    for (int k0 = 0; k0 < Khalf; k0 += 64) {
        int kk = kbase + k0;
        const u16* xp = X + (size_t)(n0 + srow) * K + kk + sseg * 16;
        uint4 xr0 = *(const uint4*)xp;
        uint4 xr1 = *(const uint4*)(xp + 8);
        uint4 wb0, wb1;
        if (flags & 32) {
            const u16* wp = (const u16*)Wp + (size_t)(m0 + srow) * K + kk + sseg * 16;
            wb0 = *(const uint4*)wp;
            wb1 = *(const uint4*)(wp + 8);
        } else {
            const float* wp = (const float*)Wp + (size_t)(m0 + srow) * K + kk + sseg * 16;
            float4 w0 = *(const float4*)wp;
            float4 w1 = *(const float4*)(wp + 4);
            float4 w2 = *(const float4*)(wp + 8);
            float4 w3 = *(const float4*)(wp + 12);
            wb0.x = pkbf(w0.x, w0.y); wb0.y = pkbf(w0.z, w0.w);
            wb0.z = pkbf(w1.x, w1.y); wb0.w = pkbf(w1.z, w1.w);
            wb1.x = pkbf(w2.x, w2.y); wb1.y = pkbf(w2.z, w2.w);
            wb1.z = pkbf(w3.x, w3.y); wb1.w = pkbf(w3.z, w3.w);
        }
        __syncthreads();
        *(uint4*)&Xs[kg][srow * LDB + sseg * 16] = xr0;
        *(uint4*)&Xs[kg][srow * LDB + sseg * 16 + 8] = xr1;
        *(uint4*)&Ws[kg][srow * LDB + sseg * 16] = wb0;
        *(uint4*)&Ws[kg][srow * LDB + sseg * 16 + 8] = wb1;
        __syncthreads();

        const u16* As = (flags & 2) ? &Ws[kg][0] : &Xs[kg][0];
        const u16* Bs = (flags & 2) ? &Xs[kg][0] : &Ws[kg][0];
#pragma unroll
        for (int h = 0; h < 2; ++h) {
            int ko = h * 32 + quad * 8;
            bf16x8 a0 = *(const bf16x8*)&As[(wy * 32 + lo16) * LDB + ko];
            bf16x8 a1 = *(const bf16x8*)&As[(wy * 32 + 16 + lo16) * LDB + ko];
            bf16x8 b0 = *(const bf16x8*)&Bs[(wx * 32 + lo16) * LDB + ko];
            bf16x8 b1 = *(const bf16x8*)&Bs[(wx * 32 + 16 + lo16) * LDB + ko];
            acc[0][0] = __builtin_amdgcn_mfma_f32_16x16x32_bf16(a0, b0, acc[0][0], 0, 0, 0);
            acc[0][1] = __builtin_amdgcn_mfma_f32_16x16x32_bf16(a0, b1, acc[0][1], 0, 0, 0);
            acc[1][0] = __builtin_amdgcn_mfma_f32_16x16x32_bf16(a1, b0, acc[1][0], 0, 0, 0);
            acc[1][1] = __builtin_amdgcn_mfma_f32_16x16x32_bf16(a1, b1, acc[1][1], 0, 0, 0);
        }
    }

    __syncthreads();
    if (kg == 1) {
        float* c = &Cred[t * 17];
#pragma unroll
        for (int i = 0; i < 2; ++i)
#pragma unroll
            for (int j = 0; j < 2; ++j)
#pragma unroll
                for (int r = 0; r < 4; ++r) c[(i * 2 + j) * 4 + r] = acc[i][j][r];
    }
    __syncthreads();
    if (kg == 1) return;
    {
        const float* c = &Cred[t * 17];
#pragma unroll
        for (int i = 0; i < 2; ++i)
#pragma unroll
            for (int j = 0; j < 2; ++j)
#pragma unroll
                for (int r = 0; r < 4; ++r) acc[i][j][r] += c[(i * 2 + j) * 4 + r];
    }

    u16* Y = (u16*)Yp;
    if (flags & 2) {
#pragma unroll
        for (int i = 0; i < 2; ++i)
#pragma unroll
            for (int r = 0; r < 4; ++r) {
                int ch = m0 + wy * 32 + i * 16 + quad * 4 + r;
                float bb = bias[ch];
#pragma unroll
                for (int j = 0; j < 2; ++j) {
                    int tok = n0 + wx * 32 + j * 16 + lo16;
                    Y[(size_t)ch * NTOK + tok] = f2bf(acc[i][j][r] + bb);
                }
            }
    } else {
        float smul = (flags & 16) ? 1.4426950408889634f / scl[0] : 1.0f;
        float bj0 = bias[m0 + wx * 32 + lo16];
        float bj1 = bias[m0 + wx * 32 + 16 + lo16];
        const float* rf = (const float*)res;
        const u16* rb = (const u16*)res;
#pragma unroll
        for (int i = 0; i < 2; ++i)
#pragma unroll
            for (int j = 0; j < 2; ++j) {
                int ch = m0 + wx * 32 + j * 16 + lo16;
                float bb = j ? bj1 : bj0;
#pragma unroll
                for (int r = 0; r < 4; ++r) {
                    int tok = n0 + wy * 32 + i * 16 + quad * 4 + r;
                    float v = (acc[i][j][r] + bb) * smul;
                    if (flags & 1) v = gelu_exact(v);
                    if (flags & 4) v += rf[(size_t)tok * M + ch];
                    if (flags & 8) v += bf2f(rb[(size_t)tok * M + ch]);
                    if (flags & 64)
                        Y[((size_t)(ch >> 5) * NTOK + tok) * 32 + (ch & 31)] = f2bf(v);
                    else
                        Y[(size_t)tok * M + ch] = f2bf(v);
                }
            }
    }
}

// ---------------- split-K flash attention, 32x32 MFMA, register P ----------------
// grid (32, 8, split): block = 128 queries (4 waves x 32q) x (niter*64) keys.
// K/V tile in double-buffered LDS, one barrier per tile. Softmax in registers
// (swapped QK^T). PV A-frags rebuilt with v_permlane32_swap (VALU pipe) instead
// of ds_bpermute: one swap yields BOTH fragment words -> zero LDS shuffle traffic.
#define LDK 40
#define LDV 72
__global__ __launch_bounds__(256) void k_fattn(const u16* __restrict__ Qh,
                                               const u16* __restrict__ Kh,
                                               const u16* __restrict__ Vc,
                                               u16* __restrict__ Op,
                                               float* __restrict__ Lp,
                                               int niter) {
    __shared__ u16 Kt[2][64 * LDK];        // 10240 B
    __shared__ u16 Vt[2][32 * LDV];        // 9216 B  (19.4 KB total)

    int h = blockIdx.y;
    int q0 = blockIdx.x * 128;
    int sp = blockIdx.z;
    int tid = threadIdx.x;
    int wid = tid >> 6, lane = tid & 63;
    int ql = lane & 31, hi = lane >> 5;
    int qtok = q0 + wid * 32 + ql;

    // stationary Q as B-operand: col=q=ql, k=d (two 16-wide d-halves)
    const u16* qp = Qh + ((size_t)h * NTOK + qtok) * 32 + hi * 8;
    bf16x8 bq0 = *(const bf16x8*)(qp);
    bf16x8 bq1 = *(const bf16x8*)(qp + 16);

    int krow = tid >> 2, kseg = tid & 3;   // 64 rows x 4 segs of 16B
    int vrow = tid >> 3, vseg = tid & 7;   // 32 rows x 8 segs of 16B
    int kbase = sp * (niter * 64);

    f32x16 oacc = {0.f, 0.f, 0.f, 0.f, 0.f, 0.f, 0.f, 0.f,
                   0.f, 0.f, 0.f, 0.f, 0.f, 0.f, 0.f, 0.f};
    const f32x16 zv = {0.f, 0.f, 0.f, 0.f, 0.f, 0.f, 0.f, 0.f,
                       0.f, 0.f, 0.f, 0.f, 0.f, 0.f, 0.f, 0.f};
    float l = 0.f;

    uint4 kreg = *(const uint4*)(Kh + ((size_t)h * NTOK + kbase + krow) * 32 + kseg * 8);
    uint4 vreg = *(const uint4*)(Vc + (size_t)(h * 32 + vrow) * NTOK + kbase + vseg * 8);

    for (int kt = 0; kt < niter; ++kt) {
        int cb = kt & 1;
        *(uint4*)&Kt[cb][krow * LDK + kseg * 8] = kreg;
        *(uint4*)&Vt[cb][vrow * LDV + vseg * 8] = vreg;
        __syncthreads();                   // single barrier per tile (dbuf)
        if (kt + 1 < niter) {              // issue next tile early, overlap compute
            int kn = kbase + (kt + 1) * 64;
            kreg = *(const uint4*)(Kh + ((size_t)h * NTOK + kn + krow) * 32 + kseg * 8);
            vreg = *(const uint4*)(Vc + (size_t)(h * 32 + vrow) * NTOK + kn + vseg * 8);
        }

#pragma unroll
        for (int sub = 0; sub < 2; ++sub) {
            // S^T[key][q] over 32 keys, d=32 via two K=16 MFMAs (C of first = zv)
            bf16x8 ak0 = *(const bf16x8*)&Kt[cb][(sub * 32 + ql) * LDK + hi * 8];
            bf16x8 ak1 = *(const bf16x8*)&Kt[cb][(sub * 32 + ql) * LDK + 16 + hi * 8];
            f32x16 s = __builtin_amdgcn_mfma_f32_32x32x16_bf16(ak0, bq0, zv, 0, 0, 0);
            s = __builtin_amdgcn_mfma_f32_32x32x16_bf16(ak1, bq1, s, 0, 0, 0);
            // p = exp2(s) (scores O(1), no max); pack pairs of adjacent keys:
            // u[t] = P[q][keys (2t&3)+8*(t>>1)+4*hi .. +1]
            u32 u[8];
#pragma unroll
            for (int t = 0; t < 8; ++t) {
                float pa = __builtin_amdgcn_exp2f(s[2 * t]);
                float pb = __builtin_amdgcn_exp2f(s[2 * t + 1]);
                l += pa + pb;
                u[t] = pkbf(pa, pb);
            }
            // rebuild PV A-fragments (row=q, k=key): m=0 -> keys sub*32+0..15,
            // m=1 -> keys sub*32+16..31.
            uint4 wa, wb;
#ifdef HAVE_PLSWAP
            // one swap yields both words: r0 = {a.lo-lanes, b.lo-lanes},
            // r1 = {a.hi-lanes, b.hi-lanes} (VALU pipe, no LDS)
            u32x2 r0 = __builtin_amdgcn_permlane32_swap(u[0], u[2], false, false);
            u32x2 r1 = __builtin_amdgcn_permlane32_swap(u[1], u[3], false, false);
            u32x2 r2 = __builtin_amdgcn_permlane32_swap(u[4], u[6], false, false);
            u32x2 r3 = __builtin_amdgcn_permlane32_swap(u[5], u[7], false, false);
            wa.x = r0[0]; wa.z = r0[1];
            wa.y = r1[0]; wa.w = r1[1];
            wb.x = r2[0]; wb.z = r2[1];
            wb.y = r3[0]; wb.w = r3[1];
#else
            u32 px[8];
#pragma unroll
            for (int t = 0; t < 8; ++t) px[t] = (u32)__shfl_xor((int)u[t], 32, 64);
            wa.x = hi ? px[2] : u[0];
            wa.y = hi ? px[3] : u[1];
            wa.z = hi ? u[2] : px[0];
            wa.w = hi ? u[3] : px[1];
            wb.x = hi ? px[6] : u[4];
            wb.y = hi ? px[7] : u[5];
            wb.z = hi ? u[6] : px[4];
            wb.w = hi ? u[7] : px[5];
#endif
            union { uint4 q; bf16x8 v; } pa0, pa1;
            pa0.q = wa; pa1.q = wb;
            // B-operand V[key][d] from d-major Vt rows: col=d=ql, k=key
            bf16x8 bv0 = *(const bf16x8*)&Vt[cb][ql * LDV + sub * 32 + hi * 8];
            bf16x8 bv1 = *(const bf16x8*)&Vt[cb][ql * LDV + sub * 32 + 16 + hi * 8];
            oacc = __builtin_amdgcn_mfma_f32_32x32x16_bf16(pa0.v, bv0, oacc, 0, 0, 0);
            oacc = __builtin_amdgcn_mfma_f32_32x32x16_bf16(pa1.v, bv1, oacc, 0, 0, 0);
        }
    }

    // l for q=ql: this lane summed its hi-half of keys; combine halves
    l += __shfl_xor(l, 32, 64);

    // O partial: rows q = (r&3)+8*(r>>2)+4*hi, col d = ql
    size_t obase = ((size_t)(sp * 8 + h) * NTOK + q0 + wid * 32) * 32 + ql;
#pragma unroll
    for (int r = 0; r < 16; ++r) {
        int qrow = (r & 3) + 8 * (r >> 2) + 4 * hi;
        Op[obase + (size_t)qrow * 32] = f2bf(oacc[r]);
    }
    if (hi == 0) Lp[(size_t)(sp * 8 + h) * NTOK + qtok] = l;
}

// ---------------- combine split partials -> fused bf16 [tok][256] ----------------
__global__ __launch_bounds__(256) void k_comb(const u16* __restrict__ Op,
                                              const float* __restrict__ Lp,
                                              u16* __restrict__ fused,
                                              int split) {
    int n = blockIdx.x * 4 + (threadIdx.x >> 6);
    int lane = threadIdx.x & 63;
    int c = lane * 4;
    int h = c >> 5, d = c & 31;
    float4 o = {0.f, 0.f, 0.f, 0.f};
    float l = 0.f;
    for (int s = 0; s < split; ++s) {
        size_t base = ((size_t)(s * 8 + h) * NTOK + n) * 32 + d;
        uint2 u = *(const uint2*)(Op + base);
        o.x += bf2f((u16)(u.x & 0xffff)); o.y += bf2f((u16)(u.x >> 16));
        o.z += bf2f((u16)(u.y & 0xffff)); o.w += bf2f((u16)(u.y >> 16));
        l += Lp[(size_t)(s * 8 + h) * NTOK + n];
    }
    float inv = 1.0f / l;
    uint2 w;
    w.x = pkbf(o.x * inv, o.y * inv);
    w.y = pkbf(o.z * inv, o.w * inv);
    *(uint2*)(fused + (size_t)n * CDIM + c) = w;
}

// ---------------- fused LN2 + transpose: out2T bf16 [4096][256] -> out f32 [256][4096]
__global__ __launch_bounds__(256) void k_lntr(const u16* __restrict__ x,
                                              const float* __restrict__ g,
                                              const float* __restrict__ b,
                                              float* __restrict__ out) {
    __shared__ float T[16][260];
    int n0 = blockIdx.x * 16;
    int t = threadIdx.x;
    int tk = t >> 4, seg = t & 15;
    float v[16];
    {
        const u16* p = x + (size_t)(n0 + tk) * CDIM + seg * 16;
        uint4 a = *(const uint4*)p;
        uint4 bq = *(const uint4*)(p + 8);
        u32 uu[8] = {a.x, a.y, a.z, a.w, bq.x, bq.y, bq.z, bq.w};
#pragma unroll
        for (int i = 0; i < 8; ++i) {
            v[2 * i] = bf2f((u16)(uu[i] & 0xffff));
            v[2 * i + 1] = bf2f((u16)(uu[i] >> 16));
        }
    }
    float s = 0.f, s2 = 0.f;
#pragma unroll
    for (int i = 0; i < 16; ++i) { s += v[i]; s2 += v[i] * v[i]; }
#pragma unroll
    for (int off = 1; off < 16; off <<= 1) {
        s += __shfl_xor(s, off, 64);
        s2 += __shfl_xor(s2, off, 64);
    }
    float mu = s * (1.0f / 256.0f);
    float var = s2 * (1.0f / 256.0f) - mu * mu;
    float rsd = rsqrtf(var + EPS_LN);
#pragma unroll
    for (int i = 0; i < 16; ++i) {
        int c = seg * 16 + i;
        T[tk][c] = (v[i] - mu) * rsd * g[c] + b[c];
    }
    __syncthreads();
    int c = t;
    float o[16];
#pragma unroll
    for (int j = 0; j < 16; ++j) o[j] = T[j][c];
    float* dst = out + (size_t)c * NTOK + n0;
#pragma unroll
    for (int j = 0; j < 4; ++j) {
        float4 w = {o[4 * j], o[4 * j + 1], o[4 * j + 2], o[4 * j + 3]};
        *(float4*)(dst + 4 * j) = w;
    }
}

// ------------------------------------------------------------------------------
extern "C" void kernel_launch(void* const* d_in, const int* in_sizes, int n_in,
                              void* d_out, int out_size, void* d_ws, size_t ws_size,
                              hipStream_t stream) {
    const float* rgb    = (const float*)d_in[0];
    const float* dpt    = (const float*)d_in[1];
    const float* x_dpt  = (const float*)d_in[2];
    const float* wq     = (const float*)d_in[3];
    const float* bq     = (const float*)d_in[4];
    const float* wk     = (const float*)d_in[5];
    const float* bk     = (const float*)d_in[6];
    const float* wv     = (const float*)d_in[7];
    const float* bv     = (const float*)d_in[8];
    const float* wo     = (const float*)d_in[9];
    const float* bo     = (const float*)d_in[10];
    const float* g_rgb  = (const float*)d_in[11];
    const float* b_rgb  = (const float*)d_in[12];
    const float* g_dpt  = (const float*)d_in[13];
    const float* b_dpt  = (const float*)d_in[14];
    const float* g1     = (const float*)d_in[15];
    const float* b1     = (const float*)d_in[16];
    const float* g2     = (const float*)d_in[17];
    const float* b2     = (const float*)d_in[18];
    const float* w_mlp1 = (const float*)d_in[19];
    const float* b_mlp1 = (const float*)d_in[20];
    const float* w_mlp2 = (const float*)d_in[21];
    const float* b_mlp2 = (const float*)d_in[22];
    const float* w_de1  = (const float*)d_in[23];
    const float* b_de1  = (const float*)d_in[24];
    const float* w_de2  = (const float*)d_in[25];
    const float* b_de2  = (const float*)d_in[26];
    const float* pos    = (const float*)d_in[27];
    const float* scale  = (const float*)d_in[28];
    float* out = (float*)d_out;

    char* base = (char*)d_ws;
    const size_t MB = 1u << 20;
    float* rgbT    = (float*)(base + 0 * MB);
    float* dptT    = (float*)(base + 4 * MB);
    u16*   outT    = (u16*)(base + 4 * MB);
    float* Lp4     = (float*)(base + 6 * MB);    // fattn..comb (512 KB, split=4 path)
    u16*   out_lnT = (u16*)(base + 6 * MB);      // ln1..mlp2 (after comb)
    u16*   relu3T  = (u16*)(base + 8 * MB);      // prep..peGEMM
    u16*   Op4     = (u16*)(base + 8 * MB);      // fattn..comb (8 MB, split=4 path)
    u16*   hT      = (u16*)(base + 8 * MB);      // mlp1..mlp2 (after comb)
    u16*   peT     = (u16*)(base + 10 * MB);     // peGEMM..LN
    u16*   aqT     = (u16*)(base + 12 * MB);     // LN..QKV
    u16*   akvT    = (u16*)(base + 14 * MB);     // LN..QKV
    u16*   Qhm     = (u16*)(base + 16 * MB);     // QKV..fattn
    u16*   out2T   = (u16*)(base + 16 * MB);     // mlp2..ln2
    u16*   Khm     = (u16*)(base + 18 * MB);
    u16*   Vcm     = (u16*)(base + 20 * MB);
    u16*   fusedT  = (u16*)(base + 22 * MB);     // comb..wo
    u16*   arena   = (u16*)(base + 24 * MB);     // bf16 weights

    bool aw = ws_size >= 26 * MB;
    int wf = aw ? 32 : 0;
    const void* Wq  = aw ? (const void*)(arena + 0)      : (const void*)wq;
    const void* Wk  = aw ? (const void*)(arena + 65536)  : (const void*)wk;
    const void* Wv  = aw ? (const void*)(arena + 131072) : (const void*)wv;
    const void* Wo  = aw ? (const void*)(arena + 196608) : (const void*)wo;
    const void* Wd2 = aw ? (const void*)(arena + 262144) : (const void*)w_de2;
    const void* Wm1 = aw ? (const void*)(arena + 327680) : (const void*)w_mlp1;
    const void* Wm2 = aw ? (const void*)(arena + 589824) : (const void*)w_mlp2;

    // split-K width for attention: 8 if workspace allows, else packed split=4.
    int split = (ws_size >= 68 * MB) ? 8 : 4;
    u16*   Op = (split == 8) ? (u16*)(base + 32 * MB) : Op4;
    float* Lp = (split == 8) ? (float*)(base + 48 * MB) : Lp4;

    // 1: transposes + downsample/conv3x3 + weight conversion
    k_prep<<<aw ? 512 + 256 + 832 : 512 + 256, 256, 0, stream>>>(
        rgb, rgbT, dpt, dptT, x_dpt, w_de1, b_de1, relu3T,
        wq, wk, wv, wo, w_de2, w_mlp1, w_mlp2, arena);
    // 2: pe = 1x1(relu3)
    k_bmm<<<dim3(64, 4, 1), 512, 0, stream>>>(relu3T, Wd2, b_de2, peT, wf,
                                              nullptr, nullptr, nullptr, nullptr, 0,
                                              nullptr, nullptr, nullptr, nullptr, 0,
                                              nullptr, nullptr, CDIM, CDIM);
    // 3: both LayerNorms (+pos+pe)
    k_lnT<<<dim3(1024, 2), 256, 0, stream>>>(rgbT, g_rgb, b_rgb, aqT,
                                             dptT, g_dpt, b_dpt, akvT,
                                             peT, pos, 1);
    // 4: QKV (q scaled+head-major, k head-major, v channel-major)
    k_bmm<<<dim3(64, 4, 3), 512, 0, stream>>>(aqT, Wq, bq, Qhm, wf | 16 | 64,
                                              akvT, Wk, bk, Khm, wf | 64,
                                              akvT, Wv, bv, Vcm, wf | 2,
                                              nullptr, scale, CDIM, CDIM);
    // 5: split-K flash attention (dbuf LDS, 1 barrier/tile, permlane P-exchange)
    k_fattn<<<dim3(32, 8, split), 256, 0, stream>>>(Qhm, Khm, Vcm, Op, Lp,
                                                    NTOK / split / 64);
    // 6: combine partials
    k_comb<<<1024, 256, 0, stream>>>(Op, Lp, fusedT, split);
    // 7: output projection + residual(rgbT)
    k_bmm<<<dim3(64, 4, 1), 512, 0, stream>>>(fusedT, Wo, bo, outT, wf | 4,
                                              nullptr, nullptr, nullptr, nullptr, 0,
                                              nullptr, nullptr, nullptr, nullptr, 0,
                                              rgbT, nullptr, CDIM, CDIM);
    // 8: LN1
    k_lnT<<<dim3(1024, 1), 256, 0, stream>>>(outT, g1, b1, out_lnT,
                                             nullptr, nullptr, nullptr, nullptr,
                                             nullptr, nullptr, 0);
    // 9: MLP up + GELU
    k_bmm<<<dim3(64, 16, 1), 512, 0, stream>>>(out_lnT, Wm1, b_mlp1, hT, wf | 1,
                                               nullptr, nullptr, nullptr, nullptr, 0,
                                               nullptr, nullptr, nullptr, nullptr, 0,
                                               nullptr, nullptr, MLPD, CDIM);
    // 10: MLP down + residual(out_lnT)
    k_bmm<<<dim3(64, 4, 1), 512, 0, stream>>>(hT, Wm2, b_mlp2, out2T, wf | 8,
                                              nullptr, nullptr, nullptr, nullptr, 0,
                                              nullptr, nullptr, nullptr, nullptr, 0,
                                              out_lnT, nullptr, CDIM, MLPD);
    // 11: fused LN2 + transpose -> out [256][4096]
    k_lntr<<<256, 256, 0, stream>>>(out2T, g2, b2, out);
}